// Round 6
// baseline (369.001 us; speedup 1.0000x reference)
//
#include <hip/hip_runtime.h>
#include <math.h>

#define NB   2048
#define DE   256
#define MEMN 16384
#define CAND_CAP 256
#define FSPL 16

typedef __attribute__((ext_vector_type(8)))  short  short8;
typedef __attribute__((ext_vector_type(16))) float  float16;

// ---------------- workspace layout (float element offsets) ----------------
static const size_t OFF_QB   = 0;          // 2048*256 bf16
static const size_t OFF_KB   = 262144;     // 16384*256 bf16
static const size_t OFF_VTB  = 2359296;    // Vt tiled [512][256][32] bf16
static const size_t OFF_LP   = 4456448;    // 16*2048
static const size_t OFF_OPB  = 4521984;    // 16*2048*256 bf16 -> end 8716288 fl (~34.9 MB, known fit)
// stats overlay (dead before flash writes Opb), relative to OFF_OPB:
static const size_t SO_A    = 0;
static const size_t SO_XA   = 65536;
static const size_t SO_XB   = 131072;
static const size_t SO_U    = 196608;
static const size_t SO_MU   = 262144;
static const size_t SO_RM   = 262400;
static const size_t SO_DIST = 262656;
static const size_t SO_SC   = 264704;
static const size_t SO_CNT  = 264712;
static const size_t SO_IMPS = 264720;
static const size_t SO_ORD  = 266768;
static const size_t SO_CK   = 268816;
static const size_t SO_MUP  = 269328;

__device__ inline unsigned short f2bf(float f) {
  unsigned u = __float_as_uint(f);
  unsigned r = (u + 0x7fffu + ((u >> 16) & 1u)) >> 16;
  return (unsigned short)r;
}
__device__ inline float bf2f(unsigned short s) {
  return __uint_as_float((unsigned)s << 16);
}

__device__ inline void bitonic_sort_u64(unsigned long long* key, int n, int tid, int nth) {
  for (int k = 2; k <= n; k <<= 1) {
    for (int j = k >> 1; j > 0; j >>= 1) {
      __syncthreads();
      for (int i = tid; i < n; i += nth) {
        int ixj = i ^ j;
        if (ixj > i) {
          unsigned long long a = key[i], b = key[ixj];
          bool up = ((i & k) == 0);
          if ((a > b) == up) { key[i] = b; key[ixj] = a; }
        }
      }
    }
  }
  __syncthreads();
}

// ---------------- mean ----------------
__global__ __launch_bounds__(256) void mupart_kernel(const float* __restrict__ z, float* __restrict__ mup) {
  int d = threadIdx.x;
  int r0 = blockIdx.x * 32;
  float s = 0.f;
  for (int r = 0; r < 32; ++r) s += z[(size_t)(r0 + r) * DE + d];
  mup[blockIdx.x * DE + d] = s;
}
__global__ __launch_bounds__(256) void mufin_kernel(const float* __restrict__ mup,
                                                    const float* __restrict__ rmean,
                                                    float* __restrict__ mu, float* __restrict__ rm) {
  int d = threadIdx.x;
  float s = 0.f;
  for (int b = 0; b < 64; ++b) s += mup[b * DE + d];
  float m = s * (1.0f / (float)NB);
  mu[d] = m;
  rm[d] = 0.99f * rmean[d] + 0.01f * m;
}

// ---------------- covariance, split-K ----------------
__global__ __launch_bounds__(256) void covzero_kernel(float* __restrict__ A) {
  A[blockIdx.x * 256 + threadIdx.x] = 0.f;
}
__global__ __launch_bounds__(256) void covpart_kernel(const float* __restrict__ z,
                                                      const float* __restrict__ mu,
                                                      float* __restrict__ A) {
  __shared__ float As[16][68];
  __shared__ float Bs[16][68];
  int tid = threadIdx.x, tx = tid & 15, ty = tid >> 4;
  int i0 = blockIdx.x * 64, j0 = blockIdx.y * 64;
  int nbase = blockIdx.z * 128;
  float acc[4][4] = {};
  for (int nt = 0; nt < 8; ++nt) {
    int n0 = nbase + nt * 16;
    for (int e = tid; e < 1024; e += 256) {
      int c = e & 63, nn = e >> 6;
      As[nn][c] = z[(size_t)(n0 + nn) * DE + i0 + c] - mu[i0 + c];
      Bs[nn][c] = z[(size_t)(n0 + nn) * DE + j0 + c] - mu[j0 + c];
    }
    __syncthreads();
#pragma unroll
    for (int nn = 0; nn < 16; ++nn) {
      float4 a4 = *(const float4*)&As[nn][ty * 4];
      float4 b4 = *(const float4*)&Bs[nn][tx * 4];
      acc[0][0] += a4.x*b4.x; acc[0][1] += a4.x*b4.y; acc[0][2] += a4.x*b4.z; acc[0][3] += a4.x*b4.w;
      acc[1][0] += a4.y*b4.x; acc[1][1] += a4.y*b4.y; acc[1][2] += a4.y*b4.z; acc[1][3] += a4.y*b4.w;
      acc[2][0] += a4.z*b4.x; acc[2][1] += a4.z*b4.y; acc[2][2] += a4.z*b4.z; acc[2][3] += a4.z*b4.w;
      acc[3][0] += a4.w*b4.x; acc[3][1] += a4.w*b4.y; acc[3][2] += a4.w*b4.z; acc[3][3] += a4.w*b4.w;
    }
    __syncthreads();
  }
  for (int r = 0; r < 4; ++r) {
    int i = i0 + ty * 4 + r;
    for (int c = 0; c < 4; ++c) {
      int j = j0 + tx * 4 + c;
      atomicAdd(&A[(size_t)i * DE + j], acc[r][c]);
    }
  }
}
__global__ __launch_bounds__(256) void covfin_kernel(const float* __restrict__ rcov, float* __restrict__ A) {
  int idx = blockIdx.x * 256 + threadIdx.x;
  int i = idx >> 8, j = idx & 255;
  float covv = A[idx] * (1.0f / (float)(NB - 1));
  A[idx] = 0.99f * rcov[idx] + 0.01f * covv + ((i == j) ? 1e-6f : 0.0f);
}

__global__ __launch_bounds__(256) void initx_kernel(const float* __restrict__ A, float* __restrict__ X) {
  int idx = blockIdx.x * 256 + threadIdx.x;
  int i = idx >> 8, j = idx & 255;
  X[idx] = ((i == j) ? 2.0f : 0.0f) - A[idx];
}

// fp32 256x256x256 NT-gemm, 32x32 tiles, grid (8,8)
__global__ __launch_bounds__(256) void ntgemm32(const float* __restrict__ A, const float* __restrict__ B,
                                                const float* __restrict__ Cin,
                                                float* __restrict__ C, float alpha, float beta) {
  __shared__ float As[16][36];
  __shared__ float Bs[16][36];
  int tid = threadIdx.x, tx = tid & 15, ty = tid >> 4;
  int i0 = blockIdx.x * 32, j0 = blockIdx.y * 32;
  float acc[2][2] = {};
  for (int kk0 = 0; kk0 < 256; kk0 += 16) {
    for (int e = tid; e < 512; e += 256) {
      int kk = e & 15, row = e >> 4;
      As[kk][row] = A[(size_t)(i0 + row) * 256 + kk0 + kk];
      Bs[kk][row] = B[(size_t)(j0 + row) * 256 + kk0 + kk];
    }
    __syncthreads();
#pragma unroll
    for (int kk = 0; kk < 16; ++kk) {
      float a0 = As[kk][ty * 2], a1 = As[kk][ty * 2 + 1];
      float b0 = Bs[kk][tx * 2], b1 = Bs[kk][tx * 2 + 1];
      acc[0][0] += a0 * b0; acc[0][1] += a0 * b1;
      acc[1][0] += a1 * b0; acc[1][1] += a1 * b1;
    }
    __syncthreads();
  }
  for (int r = 0; r < 2; ++r) {
    int i = i0 + ty * 2 + r;
    for (int c = 0; c < 2; ++c) {
      int j = j0 + tx * 2 + c;
      float v = alpha * acc[r][c];
      if (beta != 0.f) v += beta * Cin[(size_t)i * 256 + j];
      C[(size_t)i * 256 + j] = v;
    }
  }
}

// ---------------- bf16 MFMA GEMM for Q/K/V projections ----------------
// vtile: write output transposed-tiled as Vt[key/32][d(=orow)][key%32]
__global__ __launch_bounds__(256, 1) void gemm_qkv(const float* __restrict__ Af,
                                                   const float* __restrict__ Bf,
                                                   const float* __restrict__ bias, int bias_row,
                                                   unsigned short* __restrict__ C, int ldC, int vtile) {
  __shared__ unsigned short Bs[64 * 264];
  int tid = threadIdx.x;
  int w = tid >> 6, lane = tid & 63;
  int m = lane & 31, h = lane >> 5;
  int arow = blockIdx.x * 128 + w * 32 + m;
  int n0 = blockIdx.y * 64;

  short8 af[16];
#pragma unroll
  for (int kc = 0; kc < 16; ++kc) {
    const float* src = &Af[(size_t)arow * DE + kc * 16 + h * 8];
    float4 f0 = *(const float4*)&src[0];
    float4 f1 = *(const float4*)&src[4];
    short8 v;
    v[0] = (short)f2bf(f0.x); v[1] = (short)f2bf(f0.y);
    v[2] = (short)f2bf(f0.z); v[3] = (short)f2bf(f0.w);
    v[4] = (short)f2bf(f1.x); v[5] = (short)f2bf(f1.y);
    v[6] = (short)f2bf(f1.z); v[7] = (short)f2bf(f1.w);
    af[kc] = v;
  }

  {
    int r = tid >> 2, q = tid & 3;
    const float* src = &Bf[(size_t)(n0 + r) * DE + q * 64];
    unsigned short* dst = &Bs[r * 264 + q * 64];
#pragma unroll
    for (int j = 0; j < 8; ++j) {
      float4 f0 = *(const float4*)&src[j * 8];
      float4 f1 = *(const float4*)&src[j * 8 + 4];
      short8 v;
      v[0] = (short)f2bf(f0.x); v[1] = (short)f2bf(f0.y);
      v[2] = (short)f2bf(f0.z); v[3] = (short)f2bf(f0.w);
      v[4] = (short)f2bf(f1.x); v[5] = (short)f2bf(f1.y);
      v[6] = (short)f2bf(f1.z); v[7] = (short)f2bf(f1.w);
      *(short8*)&dst[j * 8] = v;
    }
  }
  __syncthreads();

  float16 a0 = {}, a1 = {};
#pragma unroll
  for (int kc = 0; kc < 16; ++kc) {
    short8 b0 = *(const short8*)&Bs[(0 * 32 + m) * 264 + kc * 16 + h * 8];
    short8 b1 = *(const short8*)&Bs[(1 * 32 + m) * 264 + kc * 16 + h * 8];
    a0 = __builtin_amdgcn_mfma_f32_32x32x16_bf16(af[kc], b0, a0, 0, 0, 0);
    a1 = __builtin_amdgcn_mfma_f32_32x32x16_bf16(af[kc], b1, a1, 0, 0, 0);
  }

#pragma unroll
  for (int r = 0; r < 16; ++r) {
    int rr = (r & 3) + 8 * (r >> 2) + 4 * h;
    int orow = blockIdx.x * 128 + w * 32 + rr;
    int oc0 = n0 + m, oc1 = n0 + 32 + m;
    float bb0 = bias_row ? bias[orow] : bias[oc0];
    float bb1 = bias_row ? bias[orow] : bias[oc1];
    if (!vtile) {
      C[(size_t)orow * ldC + oc0] = f2bf(a0[r] + bb0);
      C[(size_t)orow * ldC + oc1] = f2bf(a1[r] + bb1);
    } else {
      C[(size_t)(oc0 >> 5) * 8192 + (size_t)orow * 32 + (oc0 & 31)] = f2bf(a0[r] + bb0);
      C[(size_t)(oc1 >> 5) * 8192 + (size_t)orow * 32 + (oc1 & 31)] = f2bf(a1[r] + bb1);
    }
  }
}

// dist: 4 rows per block, grid 512
__global__ __launch_bounds__(256) void dist_kernel(const float* __restrict__ z, const float* __restrict__ rm,
                                                   const float* __restrict__ X, float* __restrict__ dist) {
  __shared__ float cc[4][256];
  __shared__ float4 red[256];
  int n0 = blockIdx.x * 4, i = threadIdx.x;
  float rmi = rm[i];
#pragma unroll
  for (int r = 0; r < 4; ++r) cc[r][i] = z[(size_t)(n0 + r) * DE + i] - rmi;
  __syncthreads();
  float y0 = 0.f, y1 = 0.f, y2 = 0.f, y3 = 0.f;
#pragma unroll 8
  for (int j = 0; j < DE; ++j) {
    float x = X[(size_t)j * DE + i];
    y0 += x * cc[0][j]; y1 += x * cc[1][j]; y2 += x * cc[2][j]; y3 += x * cc[3][j];
  }
  float4 v;
  v.x = y0 * cc[0][i]; v.y = y1 * cc[1][i]; v.z = y2 * cc[2][i]; v.w = y3 * cc[3][i];
  red[i] = v;
  __syncthreads();
  for (int s = 128; s > 0; s >>= 1) {
    if (i < s) {
      float4 a = red[i], b = red[i + s];
      a.x += b.x; a.y += b.y; a.z += b.z; a.w += b.w;
      red[i] = a;
    }
    __syncthreads();
  }
  if (i < 4) {
    float4 t = red[0];
    float d = (i == 0) ? t.x : (i == 1) ? t.y : (i == 2) ? t.z : t.w;
    dist[n0 + i] = sqrtf(fmaxf(d, 1e-8f));
  }
}

__global__ __launch_bounds__(256) void scalars_kernel(const float* __restrict__ dist,
                                                      const int* __restrict__ labels,
                                                      float* __restrict__ sc, int* __restrict__ cnt) {
  __shared__ float smin[256], smax[256];
  __shared__ int scnt[256];
  int t = threadIdx.x;
  float mn = 1e30f, mx = -1e30f; int c1 = 0;
  for (int n = t; n < NB; n += 256) {
    float d = dist[n];
    mn = fminf(mn, d); mx = fmaxf(mx, d);
    c1 += labels[n];
  }
  smin[t] = mn; smax[t] = mx; scnt[t] = c1;
  __syncthreads();
  for (int s = 128; s > 0; s >>= 1) {
    if (t < s) {
      smin[t] = fminf(smin[t], smin[t + s]);
      smax[t] = fmaxf(smax[t], smax[t + s]);
      scnt[t] += scnt[t + s];
    }
    __syncthreads();
  }
  if (t == 0) {
    float p1 = (float)scnt[0] / (float)NB;
    float p0 = (float)(NB - scnt[0]) / (float)NB;
    float kl = p0 * logf(fmaxf(2.f * p0, 1e-8f)) + p1 * logf(fmaxf(2.f * p1, 1e-8f));
    kl = fmaxf(kl, 0.f);
    sc[0] = smin[0]; sc[1] = smax[0]; sc[2] = kl; sc[3] = 2.f * kl;
    *cnt = 0;
  }
}

__global__ __launch_bounds__(1024) void impsort_kernel(const float* __restrict__ dist,
                                                       const float* __restrict__ sc,
                                                       float* __restrict__ imps, int* __restrict__ ord) {
  __shared__ unsigned long long keys[NB];
  float dmin = sc[0], dmax = sc[1], kl = sc[2];
  float inv = 1.0f / (dmax - dmin + 1e-8f);
  for (int n = threadIdx.x; n < NB; n += 1024) {
    float a = (dist[n] - dmin) * inv;
    float imp = (1.0f + a) * kl;
    keys[n] = ((unsigned long long)(unsigned)(~__float_as_uint(imp)) << 32) | (unsigned)n;
  }
  bitonic_sort_u64(keys, NB, threadIdx.x, 1024);
  for (int i = threadIdx.x; i < NB; i += 1024) {
    unsigned long long kv = keys[i];
    ord[i] = (int)(kv & 0xffffffffULL);
    imps[i] = __uint_as_float(~(unsigned)(kv >> 32));
  }
}

__global__ __launch_bounds__(256) void cand_kernel(const float* __restrict__ w, const float* __restrict__ sc,
                                                   unsigned long long* __restrict__ ck, int* __restrict__ cnt) {
  int j = blockIdx.x * 256 + threadIdx.x;
  float thresh = sc[3];
  float wv = w[j];
  if (wv < thresh) {
    int p = atomicAdd(cnt, 1);
    if (p < CAND_CAP) ck[p] = ((unsigned long long)__float_as_uint(wv) << 32) | (unsigned)j;
  }
}

__global__ __launch_bounds__(256) void evict_kernel(const unsigned long long* __restrict__ ck,
                                                    const int* __restrict__ cnt,
                                                    const float* __restrict__ imps,
                                                    const int* __restrict__ ord,
                                                    const float* __restrict__ z,
                                                    float* __restrict__ memory) {
  __shared__ unsigned long long keys[CAND_CAP];
  __shared__ int slots[CAND_CAP];
  __shared__ int m_sh;
  int tid = threadIdx.x;
  int C = *cnt; if (C > CAND_CAP) C = CAND_CAP;
  for (int i = tid; i < CAND_CAP; i += 256)
    keys[i] = (i < C) ? ck[i] : 0xFFFFFFFFFFFFFFFFULL;
  bitonic_sort_u64(keys, CAND_CAP, tid, 256);
  if (tid == 0) {
    int m = 0;
    int lim = C < NB ? C : NB;
    float prev = 0.f;
    for (int i = 0; i < lim; ++i) {
      float wv = __uint_as_float((unsigned)(keys[i] >> 32));
      float im = imps[i];
      if (!(im > wv)) break;
      if (i > 0 && !(prev >= wv)) break;
      slots[m++] = (int)(keys[i] & 0xffffffffULL);
      prev = im;
    }
    m_sh = m;
  }
  __syncthreads();
  int m = m_sh;
  for (int e = tid; e < m * DE; e += 256) {
    int i = e >> 8, d = e & 255;
    memory[(size_t)slots[i] * DE + d] = z[(size_t)ord[i] * DE + d];
  }
}

// ---------------- MFMA flash attention: 64 q-rows/wave, D-split, tiled Vt ----------------
// block = 128 threads (2 waves); grid (sp, qg, dh) = (16, 16, 2) -> sp%8 = XCD affinity
__global__ __launch_bounds__(128, 1) void flash_kernel(
    const unsigned short* __restrict__ Qb, const unsigned short* __restrict__ Kb,
    const unsigned short* __restrict__ Vtb, unsigned short* __restrict__ Opb,
    float* __restrict__ Lp, int kps, int fit) {
  __shared__ unsigned short Ks[32 * 264];        // [key][256+8]
  __shared__ unsigned short Vs[128 * 40];        // [d' (this block's 128)][32+8]
  __shared__ unsigned short Ps[2][64 * 40];      // per-wave P: 64 rows x 32 keys

  int tid = threadIdx.x;
  int w = tid >> 6, lane = tid & 63;
  int m = lane & 31, h = lane >> 5;
  int sp = blockIdx.x, qg = blockIdx.y, dh = blockIdx.z;
  int qbase = qg * 128 + w * 64;

  short8 qf0[16], qf1[16];
#pragma unroll
  for (int kc = 0; kc < 16; ++kc) {
    qf0[kc] = *(const short8*)&Qb[(size_t)(qbase + m) * DE + kc * 16 + h * 8];
    qf1[kc] = *(const short8*)&Qb[(size_t)(qbase + 32 + m) * DE + kc * 16 + h * 8];
  }
  short8 ones;
#pragma unroll
  for (int j = 0; j < 8; ++j) ones[j] = (short)0x3F80;   // bf16 1.0

  float16 O0[4] = {}, O1[4] = {};
  float16 l0 = {}, l1 = {};

  // prefetch tile 0
  short8 kreg[8], vreg[4];
  {
    int kb = sp * kps;
#pragma unroll
    for (int i = 0; i < 8; ++i) {
      int c = i * 128 + tid, kr = c >> 5, kc = c & 31;
      kreg[i] = *(const short8*)&Kb[(size_t)(kb + kr) * DE + kc * 8];
    }
    const unsigned short* vg = &Vtb[(size_t)(kb >> 5) * 8192 + (size_t)(dh * 128 + tid) * 32];
#pragma unroll
    for (int j = 0; j < 4; ++j) vreg[j] = *(const short8*)&vg[j * 8];
  }

  for (int it = 0; it < fit; ++it) {
    __syncthreads();
#pragma unroll
    for (int i = 0; i < 8; ++i) {
      int c = i * 128 + tid, kr = c >> 5, kc = c & 31;
      *(short8*)&Ks[kr * 264 + kc * 8] = kreg[i];
    }
#pragma unroll
    for (int j = 0; j < 4; ++j) *(short8*)&Vs[tid * 40 + j * 8] = vreg[j];
    if (it + 1 < fit) {
      int kb = sp * kps + (it + 1) * 32;
#pragma unroll
      for (int i = 0; i < 8; ++i) {
        int c = i * 128 + tid, kr = c >> 5, kc = c & 31;
        kreg[i] = *(const short8*)&Kb[(size_t)(kb + kr) * DE + kc * 8];
      }
      const unsigned short* vg = &Vtb[(size_t)(kb >> 5) * 8192 + (size_t)(dh * 128 + tid) * 32];
#pragma unroll
      for (int j = 0; j < 4; ++j) vreg[j] = *(const short8*)&vg[j * 8];
    }
    __syncthreads();

    // S for both q-subtiles, sharing each Ks fragment in registers
    float16 sa = {}, sb = {}, sc2 = {}, sd = {};
#pragma unroll
    for (int kc = 0; kc < 16; kc += 2) {
      short8 b0 = *(const short8*)&Ks[m * 264 + kc * 16 + h * 8];
      short8 b1 = *(const short8*)&Ks[m * 264 + (kc + 1) * 16 + h * 8];
      sa  = __builtin_amdgcn_mfma_f32_32x32x16_bf16(qf0[kc],     b0, sa,  0, 0, 0);
      sb  = __builtin_amdgcn_mfma_f32_32x32x16_bf16(qf0[kc + 1], b1, sb,  0, 0, 0);
      sc2 = __builtin_amdgcn_mfma_f32_32x32x16_bf16(qf1[kc],     b0, sc2, 0, 0, 0);
      sd  = __builtin_amdgcn_mfma_f32_32x32x16_bf16(qf1[kc + 1], b1, sd,  0, 0, 0);
    }
#pragma unroll
    for (int r = 0; r < 16; ++r) {
      int row = (r & 3) + 8 * (r >> 2) + 4 * h;
      Ps[w][row * 40 + m]        = f2bf(__expf(fmaf(sa[r] + sb[r], 0.625f, -11.0903549f)));
      Ps[w][(32 + row) * 40 + m] = f2bf(__expf(fmaf(sc2[r] + sd[r], 0.625f, -11.0903549f)));
    }
    short8 pa00 = *(const short8*)&Ps[w][m * 40 + h * 8];
    short8 pa01 = *(const short8*)&Ps[w][m * 40 + 16 + h * 8];
    short8 pa10 = *(const short8*)&Ps[w][(32 + m) * 40 + h * 8];
    short8 pa11 = *(const short8*)&Ps[w][(32 + m) * 40 + 16 + h * 8];
    l0 = __builtin_amdgcn_mfma_f32_32x32x16_bf16(pa00, ones, l0, 0, 0, 0);
    l0 = __builtin_amdgcn_mfma_f32_32x32x16_bf16(pa01, ones, l0, 0, 0, 0);
    l1 = __builtin_amdgcn_mfma_f32_32x32x16_bf16(pa10, ones, l1, 0, 0, 0);
    l1 = __builtin_amdgcn_mfma_f32_32x32x16_bf16(pa11, ones, l1, 0, 0, 0);
    // PV: each Vs fragment feeds both q-subtiles
#pragma unroll
    for (int ct = 0; ct < 4; ++ct) {
      short8 vb0 = *(const short8*)&Vs[(ct * 32 + m) * 40 + h * 8];
      short8 vb1 = *(const short8*)&Vs[(ct * 32 + m) * 40 + 16 + h * 8];
      O0[ct] = __builtin_amdgcn_mfma_f32_32x32x16_bf16(pa00, vb0, O0[ct], 0, 0, 0);
      O0[ct] = __builtin_amdgcn_mfma_f32_32x32x16_bf16(pa01, vb1, O0[ct], 0, 0, 0);
      O1[ct] = __builtin_amdgcn_mfma_f32_32x32x16_bf16(pa10, vb0, O1[ct], 0, 0, 0);
      O1[ct] = __builtin_amdgcn_mfma_f32_32x32x16_bf16(pa11, vb1, O1[ct], 0, 0, 0);
    }
  }

  size_t ob0 = ((size_t)sp * NB + qbase) * DE + dh * 128;
  size_t ob1 = ((size_t)sp * NB + qbase + 32) * DE + dh * 128;
#pragma unroll
  for (int ct = 0; ct < 4; ++ct)
#pragma unroll
    for (int r = 0; r < 16; ++r) {
      int rr = (r & 3) + 8 * (r >> 2) + 4 * h;
      Opb[ob0 + (size_t)rr * DE + ct * 32 + m] = f2bf(O0[ct][r]);
      Opb[ob1 + (size_t)rr * DE + ct * 32 + m] = f2bf(O1[ct][r]);
    }
  if (dh == 0 && m == 0) {
#pragma unroll
    for (int r = 0; r < 16; ++r) {
      int rr = (r & 3) + 8 * (r >> 2) + 4 * h;
      Lp[sp * NB + qbase + rr]      = l0[r];
      Lp[sp * NB + qbase + 32 + rr] = l1[r];
    }
  }
}

__global__ __launch_bounds__(256) void combine_kernel(const float* __restrict__ z,
                                                      const unsigned short* __restrict__ Opb,
                                                      const float* __restrict__ Lp,
                                                      float* __restrict__ out, int spl) {
  int n = blockIdx.x, c = threadIdx.x;
  float num = 0.f, den = 0.f;
  for (int s = 0; s < spl; ++s) {
    den += Lp[s * NB + n];
    num += bf2f(Opb[((size_t)s * NB + n) * DE + c]);
  }
  size_t base = (size_t)n * DE + c;
  out[base] = z[base] + 0.5f * num / den;
}

// ---------------- launcher ----------------
extern "C" void kernel_launch(void* const* d_in, const int* in_sizes, int n_in,
                              void* d_out, int out_size, void* d_ws, size_t ws_size,
                              hipStream_t stream) {
  (void)in_sizes; (void)n_in; (void)out_size; (void)ws_size;
  const float* z       = (const float*)d_in[0];
  const int*   labels  = (const int*)d_in[1];
  float*       memory  = (float*)d_in[2];
  const float* weights = (const float*)d_in[3];
  const float* rmean   = (const float*)d_in[4];
  const float* rcov    = (const float*)d_in[5];
  const float* Wq      = (const float*)d_in[6];
  const float* bq      = (const float*)d_in[7];
  const float* Wk      = (const float*)d_in[8];
  const float* bk      = (const float*)d_in[9];
  const float* Wv      = (const float*)d_in[10];
  const float* bv      = (const float*)d_in[11];
  float* out = (float*)d_out;
  float* ws  = (float*)d_ws;

  unsigned short* Qbf = (unsigned short*)(ws + OFF_QB);
  unsigned short* Kbf = (unsigned short*)(ws + OFF_KB);
  unsigned short* Vtb = (unsigned short*)(ws + OFF_VTB);
  float* Lp           = ws + OFF_LP;
  unsigned short* Opb = (unsigned short*)(ws + OFF_OPB);
  float* SB   = ws + OFF_OPB;
  float* A    = SB + SO_A;
  float* Xa   = SB + SO_XA;
  float* Xb   = SB + SO_XB;
  float* U    = SB + SO_U;
  float* mu   = SB + SO_MU;
  float* rm   = SB + SO_RM;
  float* dist = SB + SO_DIST;
  float* sc   = SB + SO_SC;
  int*   cnt  = (int*)(SB + SO_CNT);
  float* imps = SB + SO_IMPS;
  int*   ord  = (int*)(SB + SO_ORD);
  unsigned long long* ck = (unsigned long long*)(SB + SO_CK);
  float* mup  = SB + SO_MUP;

  const int spl = FSPL;              // grid (16,16,2) = 512 blocks = 2 blocks/CU
  const int kps = MEMN / spl, fit = kps / 32;

  mupart_kernel<<<64, 256, 0, stream>>>(z, mup);
  mufin_kernel<<<1, 256, 0, stream>>>(mup, rmean, mu, rm);
  covzero_kernel<<<256, 256, 0, stream>>>(A);
  covpart_kernel<<<dim3(4, 4, 16), 256, 0, stream>>>(z, mu, A);
  covfin_kernel<<<256, 256, 0, stream>>>(rcov, A);
  initx_kernel<<<256, 256, 0, stream>>>(A, Xa);
  float* Xc = Xa; float* Xn = Xb;
  for (int it = 0; it < 2; ++it) {   // Newton-Schulz (cond(A)~1.02)
    ntgemm32<<<dim3(8, 8), 256, 0, stream>>>(Xc, A, nullptr, U, 1.f, 0.f);
    ntgemm32<<<dim3(8, 8), 256, 0, stream>>>(U, Xc, Xc, Xn, -1.f, 2.f);
    float* t = Xc; Xc = Xn; Xn = t;
  }
  dist_kernel<<<NB / 4, 256, 0, stream>>>(z, rm, Xc, dist);
  scalars_kernel<<<1, 256, 0, stream>>>(dist, labels, sc, cnt);
  impsort_kernel<<<1, 1024, 0, stream>>>(dist, sc, imps, ord);
  cand_kernel<<<MEMN / 256, 256, 0, stream>>>(weights, sc, ck, cnt);
  evict_kernel<<<1, 256, 0, stream>>>(ck, cnt, imps, ord, z, memory);
  gemm_qkv<<<dim3(NB / 128, DE / 64), 256, 0, stream>>>(z, Wq, bq, 0, Qbf, DE, 0);
  gemm_qkv<<<dim3(MEMN / 128, DE / 64), 256, 0, stream>>>(memory, Wk, bk, 0, Kbf, DE, 0);
  gemm_qkv<<<dim3(DE / 128, MEMN / 64), 256, 0, stream>>>(Wv, memory, bv, 1, Vtb, 0, 1);
  flash_kernel<<<dim3(spl, NB / 128, 2), 128, 0, stream>>>(Qbf, Kbf, Vtb, Opb, Lp, kps, fit);
  combine_kernel<<<NB, 256, 0, stream>>>(z, Opb, Lp, out, spl);
}